// Round 3
// baseline (361.994 us; speedup 1.0000x reference)
//
#include <hip/hip_runtime.h>
#include <math.h>

#define CLS 1000          // number of classes
#define VEC_PER_ROW 250   // 1000 / 4 float4s per row
#define BETA 3.0f
#define NPART 256         // partial sums for final reduction
#define LOG2E 1.44269504088896f

// ---------------------------------------------------------------------------
// Kernel A: one wave (64 lanes) per row, 4 rows per 256-thread block.
// Each lane holds its <=16 row elements in registers (4x float4).
// Pass 1 (registers): row max via fmax tree + 6-step butterfly.
// Pass 2 (registers): S = sum exp2(x*log2e - m*log2e)  [fma feeds v_exp_f32],
//   4 independent accumulators; argmax = min index where x==m.
// Lane 0: direct-loads target logit (row is L2-hot), writes logp/pred,
// scatters count[t,pred] += 1 and histogram h[t] += 1.
// ---------------------------------------------------------------------------
__global__ __launch_bounds__(256) void softmax_pass(
    const float* __restrict__ outputs,
    const int* __restrict__ targets,
    float* __restrict__ count,       // [CLS, CLS] zeroed
    float* __restrict__ h,           // [CLS] zeroed target histogram
    float* __restrict__ logp,        // [B]
    int* __restrict__ pred,          // [B]
    int B)
{
    const int wave = threadIdx.x >> 6;
    const int lane = threadIdx.x & 63;
    const int row  = blockIdx.x * 4 + wave;
    if (row >= B) return;

    const float4* rp = (const float4*)(outputs + (size_t)row * CLS);

    float4 r[4];
#pragma unroll
    for (int k = 0; k < 4; ++k) {
        const int j = lane + 64 * k;
        if (j < VEC_PER_ROW) {
            r[k] = rp[j];
        } else {
            r[k] = make_float4(-INFINITY, -INFINITY, -INFINITY, -INFINITY);
        }
    }

    // pass 1: max only (fmax tree -> v_max3 friendly)
    float m = -INFINITY;
#pragma unroll
    for (int k = 0; k < 4; ++k)
        m = fmaxf(m, fmaxf(fmaxf(r[k].x, r[k].y), fmaxf(r[k].z, r[k].w)));
#pragma unroll
    for (int off = 32; off; off >>= 1)
        m = fmaxf(m, __shfl_xor(m, off));

    // pass 2: exp2-sum (4 accumulators) + equality argmax (min idx, x==m)
    const float nmk = -m * LOG2E;
    float s0 = 0.f, s1 = 0.f, s2 = 0.f, s3 = 0.f;
    int idx = 0x7fffffff;
#pragma unroll
    for (int k = 0; k < 4; ++k) {
        const int base = (lane + 64 * k) * 4;
        s0 += exp2f(fmaf(r[k].x, LOG2E, nmk));   // tail: exp2(-inf) = 0
        s1 += exp2f(fmaf(r[k].y, LOG2E, nmk));
        s2 += exp2f(fmaf(r[k].z, LOG2E, nmk));
        s3 += exp2f(fmaf(r[k].w, LOG2E, nmk));
        if (r[k].x == m) idx = min(idx, base);
        if (r[k].y == m) idx = min(idx, base + 1);
        if (r[k].z == m) idx = min(idx, base + 2);
        if (r[k].w == m) idx = min(idx, base + 3);
    }
    float S = (s0 + s1) + (s2 + s3);
#pragma unroll
    for (int off = 32; off; off >>= 1) {
        S   += __shfl_xor(S, off);
        idx  = min(idx, __shfl_xor(idx, off));
    }

    if (lane == 0) {
        const int t    = targets[row];
        const float xt = outputs[(size_t)row * CLS + t];  // L2-hot gather
        logp[row] = xt - m - __log2f(S) * (1.0f / LOG2E);
        pred[row] = idx;
        atomicAdd(&count[(size_t)t * CLS + idx], 1.0f);
        atomicAdd(&h[t], 1.0f);
    }
}

// ---------------------------------------------------------------------------
// Kernel B: rowsum0[t] = sum_p cost_matrix[t, p].  One wave per row.
// Independent of softmax_pass (reads only the input cost matrix).
// ---------------------------------------------------------------------------
__global__ __launch_bounds__(256) void rowsum0_kernel(
    const float* __restrict__ cost0,
    float* __restrict__ rowsum0)
{
    const int wave = threadIdx.x >> 6;
    const int lane = threadIdx.x & 63;
    const int row  = blockIdx.x * 4 + wave;
    if (row >= CLS) return;

    const float4* rp = (const float4*)(cost0 + (size_t)row * CLS);
    float s = 0.0f;
    for (int j = lane; j < VEC_PER_ROW; j += 64) {
        const float4 v = rp[j];
        s += v.x + v.y + v.z + v.w;
    }
#pragma unroll
    for (int off = 32; off; off >>= 1) s += __shfl_xor(s, off);
    if (lane == 0) rowsum0[row] = s;
}

// ---------------------------------------------------------------------------
// Kernel C1: per-block partials of
//   sum_b logp[b] * (cost0+count)[t,p] * BETA / max(1, rowsum0[t]+h[t])
// ---------------------------------------------------------------------------
__global__ __launch_bounds__(256) void finalize_partial(
    const float* __restrict__ count,
    const float* __restrict__ cost0,
    const float* __restrict__ h,
    const float* __restrict__ rowsum0,
    const float* __restrict__ logp,
    const int* __restrict__ pred,
    const int* __restrict__ targets,
    float* __restrict__ partial,     // [NPART]
    int B)
{
    float v = 0.0f;
    for (int i = blockIdx.x * 256 + threadIdx.x; i < B; i += NPART * 256) {
        const int t = targets[i];
        const int p = pred[i];
        const size_t cell = (size_t)t * CLS + p;
        const float cm  = count[cell] + cost0[cell];
        const float rs  = rowsum0[t] + h[t];
        v += logp[i] * cm * (BETA / fmaxf(1.0f, rs));
    }
    const int lane = threadIdx.x & 63;
    const int wave = threadIdx.x >> 6;
#pragma unroll
    for (int off = 32; off; off >>= 1) v += __shfl_xor(v, off);

    __shared__ float ssum[4];
    if (lane == 0) ssum[wave] = v;
    __syncthreads();
    if (threadIdx.x == 0)
        partial[blockIdx.x] = ssum[0] + ssum[1] + ssum[2] + ssum[3];
}

// ---------------------------------------------------------------------------
// Kernel C2: reduce NPART partials, write -sum/B. No atomics, no memset.
// ---------------------------------------------------------------------------
__global__ __launch_bounds__(256) void finalize_reduce(
    const float* __restrict__ partial,
    float* __restrict__ out,
    int B)
{
    float v = (threadIdx.x < NPART) ? partial[threadIdx.x] : 0.0f;
    const int lane = threadIdx.x & 63;
    const int wave = threadIdx.x >> 6;
#pragma unroll
    for (int off = 32; off; off >>= 1) v += __shfl_xor(v, off);

    __shared__ float ssum[4];
    if (lane == 0) ssum[wave] = v;
    __syncthreads();
    if (threadIdx.x == 0)
        out[0] = -(ssum[0] + ssum[1] + ssum[2] + ssum[3]) / (float)B;
}

extern "C" void kernel_launch(void* const* d_in, const int* in_sizes, int n_in,
                              void* d_out, int out_size, void* d_ws, size_t ws_size,
                              hipStream_t stream)
{
    const float* outputs = (const float*)d_in[0];
    const int*   targets = (const int*)d_in[1];
    const float* cost0   = (const float*)d_in[2];
    const int B = in_sizes[1];

    // workspace layout (16B aligned)
    char* ws = (char*)d_ws;
    float* count   = (float*)(ws);                      // 4,000,000 B
    float* h       = (float*)(ws + 4000000);            // 4,096 B (CLS used)
    float* logp    = (float*)(ws + 4004096);            // B*4
    int*   pred    = (int*)  (ws + 4004096 + (size_t)B * 4);
    float* rowsum0 = (float*)(ws + 4004096 + (size_t)B * 8);        // 4 KB
    float* partial = (float*)(ws + 4004096 + (size_t)B * 8 + 4096); // NPART*4

    // zero count matrix + histogram in one memset (ws is poisoned 0xAA)
    hipMemsetAsync(count, 0, 4004096, stream);

    rowsum0_kernel<<<(CLS + 3) / 4, 256, 0, stream>>>(cost0, rowsum0);
    softmax_pass<<<(B + 3) / 4, 256, 0, stream>>>(outputs, targets, count, h,
                                                  logp, pred, B);
    finalize_partial<<<NPART, 256, 0, stream>>>(count, cost0, h, rowsum0,
                                                logp, pred, targets, partial, B);
    finalize_reduce<<<1, 256, 0, stream>>>(partial, (float*)d_out, B);
}